// Round 5
// baseline (82.826 us; speedup 1.0000x reference)
//
#include <hip/hip_runtime.h>

// ModalitySpecificLocalSelfAttention — MI355X. f32 I/O, bf16 MFMA internals.
// 3 compute dispatches: cvt(weights) -> qkv (conv1+conv2+v, all-coalesced
// stores, also emits xT bf16 [p][c]) -> fused attention + final conv.

typedef short short8 __attribute__((ext_vector_type(8)));
typedef float f32x4 __attribute__((ext_vector_type(4)));

#define HW_PIX 16384   // H*W
#define CH 128

// ws layout in 16-bit units
#define WQ1_OFF 0
#define WQ2_OFF 16384
#define WK1_OFF 32768
#define WK2_OFF 49152
#define WV_OFF  65536
#define WO_OFF  81920          // 128x256
#define SB_OFF  114688         // 1536 f32 (3072 shorts)
#define TQ_OFF  131072         // q slot [p][c] bf16
#define TK_OFF  (TQ_OFF + 2097152)
#define TV_OFF  (TK_OFF + 2097152)
#define XT_OFF  (TV_OFF + 2097152)   // x transposed to bf16 [p][c]

static __device__ __forceinline__ float bf2f(unsigned short u) {
    union { unsigned int i; float f; } c; c.i = ((unsigned int)u) << 16; return c.f;
}
static __device__ __forceinline__ unsigned short f2bf(float f) {
    union { unsigned int i; float f; } c; c.f = f;
    unsigned int x = c.i;
    return (unsigned short)((x + 0x7fffu + ((x >> 16) & 1u)) >> 16);  // RNE
}

// ---- weights + scale/bias f32 -> canonical bf16/f32 ws ----
struct CvtArgs { const float* w[6]; const float* sb[12]; };

__global__ __launch_bounds__(256)
void cvt_k(CvtArgs a, short* __restrict__ ws)
{
    const int u = blockIdx.x * 256 + threadIdx.x;   // 62 blocks = 15872 units
    if (u < 14336) {                                 // 114688 weight elems
        const int s0 = u * 8;
        const int seg = (s0 < 81920) ? (s0 >> 14) : 5;
        const int base = (seg < 5) ? (seg << 14) : 81920;
        const float* fp = a.w[seg] + (s0 - base);
        short8 o;
        #pragma unroll
        for (int j = 0; j < 8; ++j) o[j] = (short)f2bf(fp[j]);
        *(short8*)(ws + s0) = o;
    } else if (u < 15872) {                          // 1536 scale/bias floats
        const int idx = u - 14336;
        ((float*)(ws + SB_OFF))[idx] = a.sb[idx >> 7][idx & 127];
    }
}

// ---- shared GEMM pieces (16x16x32 bf16 MFMA; wave = 16 px x 64 och) ----
__device__ __forceinline__ void gemm_frags(const short8 af[4], const short* __restrict__ W,
                                           int o0, int l16, int g, f32x4 acc[4])
{
    #pragma unroll
    for (int kk = 0; kk < 4; ++kk) {
        #pragma unroll
        for (int nt = 0; nt < 4; ++nt) {
            short8 bv = *(const short8*)(W + (o0 + nt * 16 + l16) * 128 + kk * 32 + g * 8);
            acc[nt] = __builtin_amdgcn_mfma_f32_16x16x32_bf16(af[kk], bv, acc[nt], 0, 0, 0);
        }
    }
}

__device__ __forceinline__ void epi_to_lds(const f32x4 acc[4], const float* s, const float* b,
                                           short* tile, int pg, int g, int l16, int o0)
{
    #pragma unroll
    for (int nt = 0; nt < 4; ++nt) {
        const int o = o0 + nt * 16 + l16;
        const float sf = s[o], bf = b[o];
        #pragma unroll
        for (int i = 0; i < 4; ++i) {
            const float vl = fmaxf(acc[nt][i] * sf + bf, 0.f);   // q1/k1/v/q2/k2 all ReLU
            tile[(pg * 16 + g * 4 + i) * 136 + o] = (short)f2bf(vl);
        }
    }
}

// ---- fused q=conv2(conv1(x)), k=conv2(conv1(x)), v=conv(x); also writes xT ----
__global__ __launch_bounds__(256)
void qkv_k(const float* __restrict__ x, short* __restrict__ ws)
{
    const float* sb = (const float*)(ws + SB_OFF);
    const int tid = threadIdx.x;
    const int l16 = tid & 15;
    const int g   = (tid & 63) >> 4;
    const int wv  = tid >> 6;
    const int pg  = wv >> 1, og = wv & 1;
    const int p0b = blockIdx.x * 32;
    const int p_row = p0b + pg * 16 + l16;
    const int o0  = og * 64;

    __shared__ short tileQ[32 * 136];
    __shared__ short tileK[32 * 136];
    __shared__ short tileV[32 * 136];

    // x A-fragments (f32 [c][p] -> bf16), loaded once, reused for q1/k1/v
    short8 xa[4];
    #pragma unroll
    for (int kk = 0; kk < 4; ++kk) {
        const float* src = x + (kk * 32 + g * 8) * HW_PIX + p_row;
        #pragma unroll
        for (int j = 0; j < 8; ++j) xa[kk][j] = (short)f2bf(src[j * HW_PIX]);
    }
    if (og == 0) {   // emit xT bf16 [p][c]; waves 0,2 cover all 32 px x 128 ch
        #pragma unroll
        for (int kk = 0; kk < 4; ++kk)
            *(short8*)(ws + XT_OFF + p_row * CH + kk * 32 + g * 8) = xa[kk];
    }

    f32x4 acc[4];
    const f32x4 z = {0.f, 0.f, 0.f, 0.f};

    #pragma unroll
    for (int nt = 0; nt < 4; ++nt) acc[nt] = z;
    gemm_frags(xa, ws + WQ1_OFF, o0, l16, g, acc);
    epi_to_lds(acc, sb + 0 * 128, sb + 1 * 128, tileQ, pg, g, l16, o0);

    #pragma unroll
    for (int nt = 0; nt < 4; ++nt) acc[nt] = z;
    gemm_frags(xa, ws + WK1_OFF, o0, l16, g, acc);
    epi_to_lds(acc, sb + 4 * 128, sb + 5 * 128, tileK, pg, g, l16, o0);

    #pragma unroll
    for (int nt = 0; nt < 4; ++nt) acc[nt] = z;
    gemm_frags(xa, ws + WV_OFF, o0, l16, g, acc);
    epi_to_lds(acc, sb + 8 * 128, sb + 9 * 128, tileV, pg, g, l16, o0);

    __syncthreads();

    // q2/k2 over LDS tiles (keep both accs in regs until all reads are done)
    short8 lf[4];
    const short* rowQ = tileQ + (pg * 16 + l16) * 136;
    #pragma unroll
    for (int kk = 0; kk < 4; ++kk) lf[kk] = *(const short8*)(rowQ + kk * 32 + g * 8);
    f32x4 accQ[4];
    #pragma unroll
    for (int nt = 0; nt < 4; ++nt) accQ[nt] = z;
    gemm_frags(lf, ws + WQ2_OFF, o0, l16, g, accQ);

    const short* rowK = tileK + (pg * 16 + l16) * 136;
    #pragma unroll
    for (int kk = 0; kk < 4; ++kk) lf[kk] = *(const short8*)(rowK + kk * 32 + g * 8);
    f32x4 accK[4];
    #pragma unroll
    for (int nt = 0; nt < 4; ++nt) accK[nt] = z;
    gemm_frags(lf, ws + WK2_OFF, o0, l16, g, accK);

    __syncthreads();   // all tileQ/tileK reads complete before overwrite

    epi_to_lds(accQ, sb + 2 * 128, sb + 3 * 128, tileQ, pg, g, l16, o0);
    epi_to_lds(accK, sb + 6 * 128, sb + 7 * 128, tileK, pg, g, l16, o0);

    __syncthreads();

    // coalesced store phase: 16B/lane from LDS tiles -> q, k, v slots
    #pragma unroll
    for (int pass = 0; pass < 2; ++pass) {
        const int u = tid + pass * 256;            // 512 units of 8 elems
        const int row = u >> 4, c8 = u & 15;
        const int doff = (p0b + row) * CH + c8 * 8;
        const int soff = row * 136 + c8 * 8;
        *(short8*)(ws + TQ_OFF + doff) = *(const short8*)(tileQ + soff);
        *(short8*)(ws + TK_OFF + doff) = *(const short8*)(tileK + soff);
        *(short8*)(ws + TV_OFF + doff) = *(const short8*)(tileV + soff);
    }
}

// ---- fused 7x7 attention + final conv (K=256) -> d_out f32 [c][p] ----
__global__ __launch_bounds__(256)
void fused_k(const short* __restrict__ ws, float* __restrict__ out)
{
    const short* q  = ws + TQ_OFF;
    const short* k  = ws + TK_OFF;
    const short* v  = ws + TV_OFF;
    const short* xT = ws + XT_OFF;
    const short* Wo = ws + WO_OFF;
    const float* sb = (const float*)(ws + SB_OFF);

    __shared__ short lds[128 * 40];   // phase1: att tile [32][136]; phase2: out tile

    const int tid = threadIdx.x;
    const int p0b = blockIdx.x * 32;

    // ---- phase 1: attention, 8 lanes/px, 16 ch/lane ----
    {
        const int lane8 = tid & 7;
        const int prow = tid >> 3;             // 0..31
        const int p = p0b + prow;
        const int h = p >> 7, w = p & 127;
        const int cb = lane8 * 16;

        float qf[16];
        {
            short8 a = *(const short8*)(q + p * CH + cb);
            short8 b = *(const short8*)(q + p * CH + cb + 8);
            #pragma unroll
            for (int j = 0; j < 8; ++j) {
                qf[j] = bf2f((unsigned short)a[j]);
                qf[8 + j] = bf2f((unsigned short)b[j]);
            }
        }

        float e[49];
        #pragma unroll
        for (int off = 0; off < 49; ++off) {
            const int di = off / 7 - 3, dj = off % 7 - 3;
            const int hh = h + di, ww = w + dj;
            const bool valid = ((unsigned)hh < 128u) && ((unsigned)ww < 128u);
            float t = 0.f;
            if (valid) {
                const short* kr = k + (p + di * 128 + dj) * CH + cb;
                short8 a = *(const short8*)kr;
                short8 b = *(const short8*)(kr + 8);
                #pragma unroll
                for (int j = 0; j < 8; ++j) {
                    t += qf[j] * bf2f((unsigned short)a[j]);
                    t += qf[8 + j] * bf2f((unsigned short)b[j]);
                }
            }
            t += __shfl_xor(t, 1, 8);
            t += __shfl_xor(t, 2, 8);
            t += __shfl_xor(t, 4, 8);
            e[off] = valid ? t : 0.f;
        }

        float m = e[0];
        #pragma unroll
        for (int off = 1; off < 49; ++off) m = fmaxf(m, e[off]);
        float Z = 0.f;
        #pragma unroll
        for (int off = 0; off < 49; ++off) { const float ex = __expf(e[off] - m); e[off] = ex; Z += ex; }
        const float rz = 1.0f / Z;

        float of[16];
        #pragma unroll
        for (int j = 0; j < 16; ++j) of[j] = 0.f;
        #pragma unroll
        for (int off = 0; off < 49; ++off) {
            const int di = off / 7 - 3, dj = off % 7 - 3;
            const int hh = h + di, ww = w + dj;
            if (((unsigned)hh < 128u) && ((unsigned)ww < 128u)) {
                const short* vr = v + (p + di * 128 + dj) * CH + cb;
                short8 a = *(const short8*)vr;
                short8 b = *(const short8*)(vr + 8);
                const float ev = e[off];
                #pragma unroll
                for (int j = 0; j < 8; ++j) {
                    of[j]     += ev * bf2f((unsigned short)a[j]);
                    of[8 + j] += ev * bf2f((unsigned short)b[j]);
                }
            }
        }
        short8 oa, ob;
        #pragma unroll
        for (int j = 0; j < 8; ++j) {
            oa[j] = (short)f2bf(of[j] * rz);
            ob[j] = (short)f2bf(of[8 + j] * rz);
        }
        *(short8*)(lds + prow * 136 + cb)     = oa;   // att tile [32][136]
        *(short8*)(lds + prow * 136 + cb + 8) = ob;
    }
    __syncthreads();

    // ---- phase 2: GEMM 32px x 128och x K=256 (att | xT), then f32 [c][p] out ----
    const int l16 = tid & 15;
    const int g   = (tid & 63) >> 4;
    const int wv  = tid >> 6;
    const int pg  = wv >> 1, og = wv & 1;
    const int o0  = og * 64;
    const int p_loc = pg * 16 + l16;

    f32x4 acc[4];
    const f32x4 z = {0.f, 0.f, 0.f, 0.f};
    #pragma unroll
    for (int nt = 0; nt < 4; ++nt) acc[nt] = z;

    #pragma unroll
    for (int kk = 0; kk < 8; ++kk) {
        const int kbase = kk * 32 + g * 8;
        short8 av;
        if (kk < 4) {                              // attention half from LDS
            av = *(const short8*)(lds + p_loc * 136 + kbase);
        } else {                                   // x half from xT bf16 [p][c]
            av = *(const short8*)(xT + (p0b + p_loc) * CH + (kbase - 128));
        }
        #pragma unroll
        for (int nt = 0; nt < 4; ++nt) {
            short8 bv = *(const short8*)(Wo + (o0 + nt * 16 + l16) * 256 + kbase);
            acc[nt] = __builtin_amdgcn_mfma_f32_16x16x32_bf16(av, bv, acc[nt], 0, 0, 0);
        }
    }

    __syncthreads();   // att-tile reads done before LDS reuse as out tile

    const float* s = sb + 10 * 128;
    const float* b = sb + 11 * 128;
    #pragma unroll
    for (int nt = 0; nt < 4; ++nt) {
        const int o = o0 + nt * 16 + l16;
        const float sf = s[o], bf = b[o];
        #pragma unroll
        for (int i = 0; i < 4; ++i) {
            const float vl = acc[nt][i] * sf + bf;          // no ReLU
            lds[o * 40 + pg * 16 + g * 4 + i] = (short)f2bf(vl);
        }
    }
    __syncthreads();
    #pragma unroll
    for (int pass = 0; pass < 2; ++pass) {
        const int u = tid + pass * 256;        // 512 units of 8 elems
        const int o_r = u >> 2, q4 = u & 3;
        short8 val = *(const short8*)(&lds[o_r * 40 + q4 * 8]);
        const int doff = o_r * HW_PIX + p0b + q4 * 8;
        f32x4 lo, hi;
        #pragma unroll
        for (int j = 0; j < 4; ++j) {
            lo[j] = bf2f((unsigned short)val[j]);
            hi[j] = bf2f((unsigned short)val[4 + j]);
        }
        *(f32x4*)(out + doff)     = lo;
        *(f32x4*)(out + doff + 4) = hi;
    }
}

extern "C" void kernel_launch(void* const* d_in, const int* in_sizes, int n_in,
                              void* d_out, int out_size, void* d_ws, size_t ws_size,
                              hipStream_t stream)
{
    const float* x = (const float*)d_in[0];
    short* ws = (short*)d_ws;

    CvtArgs ca;
    ca.w[0] = (const float*)d_in[1];   // w_q1
    ca.w[1] = (const float*)d_in[4];   // w_q2
    ca.w[2] = (const float*)d_in[7];   // w_k1
    ca.w[3] = (const float*)d_in[10];  // w_k2
    ca.w[4] = (const float*)d_in[13];  // w_v
    ca.w[5] = (const float*)d_in[16];  // w_o
    ca.sb[0]  = (const float*)d_in[2];  ca.sb[1]  = (const float*)d_in[3];
    ca.sb[2]  = (const float*)d_in[5];  ca.sb[3]  = (const float*)d_in[6];
    ca.sb[4]  = (const float*)d_in[8];  ca.sb[5]  = (const float*)d_in[9];
    ca.sb[6]  = (const float*)d_in[11]; ca.sb[7]  = (const float*)d_in[12];
    ca.sb[8]  = (const float*)d_in[14]; ca.sb[9]  = (const float*)d_in[15];
    ca.sb[10] = (const float*)d_in[17]; ca.sb[11] = (const float*)d_in[18];

    cvt_k<<<dim3(62), dim3(256), 0, stream>>>(ca, ws);
    qkv_k<<<dim3(512), dim3(256), 0, stream>>>(x, ws);
    fused_k<<<dim3(512), dim3(256), 0, stream>>>(ws, (float*)d_out);
}